// Round 5
// baseline (1027.126 us; speedup 1.0000x reference)
//
#include <hip/hip_runtime.h>
#include <math.h>

#define NXQ 729
#define M2Q 128
#define MQ  857
#define BQ  16
#define QPEN_ 0.1
#define SIGMA_ 0.1

typedef double d4 __attribute__((ext_vector_type(4)));

// workspace offsets (in doubles)
constexpr int OFF_P    = 0;                        // 16x729
constexpr int OFF_H2   = OFF_P + BQ*NXQ;           // 128
constexpr int OFF_Q2   = OFF_H2 + M2Q;             // 16x128 (init -> pre-loop ps only)
constexpr int OFF_TP   = OFF_Q2 + BQ*M2Q;          // 12x16x128 t partials
// ping-pong state: 2 sets x 16 batches x STB
constexpr int ST_Z    = 0;      // 729
constexpr int ST_S    = 729;    // 857
constexpr int ST_LAM  = 1586;   // 857
constexpr int ST_RP   = 2443;   // 857
constexpr int ST_V    = 3300;   // 857
constexpr int ST_AINV = 4157;   // 729
constexpr int ST_Y    = 4886;   // 729
constexpr int ST_GZ   = 5615;   // 128
constexpr int STB     = 5743;
constexpr int OFF_ST  = OFF_TP + 12*BQ*M2Q;
constexpr int OFF_SG  = OFF_ST + 2*BQ*STB;         // 16 x 10 lower tiles x 1024, tile-major

// fused-kernel LDS layout (doubles): solve region 0..16512 reused by dps phases.
constexpr int L_SL   = 0;                  // 128 x 129 = 16512 (solve only)
constexpr int L_US   = 16512;              // 128  (u — persists into dps phases)
constexpr int L_INVD = 16640;              // 128  (invd; reused as g2b after back-subst)
constexpr int L_RED2 = 16768;              // 32 x 17 = 544
constexpr int SH_FUSED = (16768 + 544) * 8;   // 138496 B -> 1 block/CU
// dps-phase aliases inside the dead Sl region:
constexpr int D_DZ   = 0;      // 729 (pad 736)
constexpr int D_RED  = 736;    // 8
constexpr int D_SC   = 744;    // 8
constexpr int D_Q2   = 752;    // 128
constexpr int D_YL   = 880;    // 64
constexpr int D_SN   = 944;    // 857
constexpr int D_LN   = 1801;   // 857
constexpr int D_PART = 2658;   // 512 (ends 3170)
constexpr int D_PSUM = 4096;   // 2x1024 sbuild MFMA partials (ends 6144)
constexpr int D_AINV = 12672;  // 729 (ends 13401) — disjoint from psum
// ps-kernel LDS: uvec 128 + part 512 + yl 64 = 704, psum at 704
constexpr int P_PSUM = 704;
constexpr int SH_PS  = (704 + 2048) * 8;   // 22016 B

__device__ __constant__ int TRI_R[10] = {0,1,1,2,2,2,3,3,3,3};
__device__ __constant__ int TRI_C[10] = {0,0,1,0,1,2,0,1,2,3};
// lower-triangle tile enumeration up to 7x7 (trailing update, r>=c)
__device__ __constant__ int TRL_R[28] = {0,1,1,2,2,2,3,3,3,3,4,4,4,4,4,5,5,5,5,5,5,6,6,6,6,6,6,6};
__device__ __constant__ int TRL_C[28] = {0,0,1,0,1,2,0,1,2,3,0,1,2,3,4,0,1,2,3,4,5,0,1,2,3,4,5,6};

__device__ __forceinline__ double wred_sum(double v) {
#pragma unroll
  for (int off = 32; off > 0; off >>= 1) v += __shfl_down(v, off, 64);
  return v;
}
__device__ __forceinline__ double wred_min(double v) {
#pragma unroll
  for (int off = 32; off > 0; off >>= 1) v = fmin(v, __shfl_down(v, off, 64));
  return v;
}
__device__ __forceinline__ double rsqrt64(double x) {
  double r = (double)rsqrtf((float)x);
  r = r * (1.5 - 0.5 * x * r * r);
  r = r * (1.5 - 0.5 * x * r * r);
  return r;
}

// C/D lane->(row,col) map for mfma_f64_16x16x4, derived at runtime via
// identity-MFMA (same trick as the solve phase).
__device__ __forceinline__ void mfma_cdmap(int* rowm, int* colm) {
  const int lane = threadIdx.x & 63;
  const int rc = lane & 15, kq = lane >> 4;
  const double avr = (kq == 0) ? (double)rc : 0.0;
  const double bv1 = (kq == 0) ? 1.0 : 0.0;
  const double av1 = (kq == 0) ? 1.0 : 0.0;
  const double bvc = (kq == 0) ? (double)rc : 0.0;
  d4 zero = {0.0, 0.0, 0.0, 0.0};
  d4 dr = __builtin_amdgcn_mfma_f64_16x16x4f64(avr, bv1, zero, 0, 0, 0);
  d4 dc = __builtin_amdgcn_mfma_f64_16x16x4f64(av1, bvc, zero, 0, 0, 0);
#pragma unroll
  for (int e = 0; e < 4; ++e) { rowm[e] = (int)dr[e]; colm[e] = (int)dc[e]; }
}

// ---------------------------------------------------------------------------
// init: grid 144 x 512 (verbatim)
// ---------------------------------------------------------------------------
__global__ __launch_bounds__(512)
void init_kernel(const float* __restrict__ puzzles, const float* __restrict__ G2,
                 const float* __restrict__ z2in, const float* __restrict__ s2in,
                 double* __restrict__ ws) {
  const int blk = blockIdx.x;
  const int tid = threadIdx.x, wave = tid >> 6, lane = tid & 63;
  __shared__ double sm[32];
  if (blk < BQ) {
    const int bb = blk;
    double* st = ws + OFF_ST + bb * STB;   // set 0
    for (int i = tid; i < NXQ; i += 512) {
      ws[OFF_P + bb * NXQ + i] = -(double)puzzles[bb * NXQ + i];
      st[ST_Z + i] = 0.0;
      st[ST_AINV + i] = 1.0 / (QPEN_ + 1.0);
      st[ST_RP + i] = 1.0;
      st[ST_V + i] = SIGMA_;
    }
    for (int i = tid; i < MQ; i += 512) { st[ST_S + i] = 1.0; st[ST_LAM + i] = 1.0; }
    if (tid < M2Q) st[ST_GZ + tid] = 0.0;
  } else {
    const int r = blk - 16;
    double acc = 0.0;
    for (int kx = tid; kx < NXQ; kx += 512)
      acc += (double)G2[r * NXQ + kx] * (double)z2in[kx];
    acc = wred_sum(acc);
    if (lane == 0) sm[wave] = acc;
    __syncthreads();
    if (tid == 0) {
      double t = 0.0;
#pragma unroll
      for (int w = 0; w < 8; ++w) t += sm[w];
      const double h2r = t + (double)s2in[r];
      ws[OFF_H2 + r] = h2r;
      sm[16] = h2r;
    }
    __syncthreads();
    if (tid < BQ) {
      double* st = ws + OFF_ST + tid * STB;
      const double rp2 = 1.0 - sm[16];
      st[ST_RP + NXQ + r] = rp2;
      st[ST_V  + NXQ + r] = rp2 - 0.9;
      ws[OFF_Q2 + tid * M2Q + r] = rp2 + 0.1;
    }
  }
}

// ---------------------------------------------------------------------------
// sbuild via f64 MFMA: S_tile(32x32) = (G2 rows R0.. * ainv) * (G2 rows C0..)^T,
// K = 729. 8 waves: wave = khalf*4 + unit; unit -> 16x16 sub-tile (sh,chh),
// khalf -> k-range half (0..367 / 368..735, zero-padded past 728).
// Operands loaded per-lane from L2-resident G2 (no LDS staging). 4 acc chains
// for ILP; partials combined via psum (2x1024 doubles in LDS).
// ---------------------------------------------------------------------------
__device__ __forceinline__ void sbuild_mfma(const float* __restrict__ G2,
                                            const double* __restrict__ ainv,
                                            double* __restrict__ psum,
                                            double* __restrict__ Sgb, const int tile,
                                            const int* rowm, const int* colm) {
  const int tid = threadIdx.x, wave = tid >> 6, lane = tid & 63;
  const int R0 = TRI_R[tile] * 32, C0 = TRI_C[tile] * 32;
  const int unit = wave & 3, khalf = wave >> 2;
  const int sh = unit >> 1, chh = unit & 1;
  const int rc = lane & 15, kq = lane >> 4;
  const float* gA = G2 + (R0 + sh * 16 + rc) * NXQ;
  const float* gB = G2 + (C0 + chh * 16 + rc) * NXQ;
  const int kbase = khalf * 368;
  d4 c0v = {0.0, 0.0, 0.0, 0.0}, c1v = c0v, c2v = c0v, c3v = c0v;
  for (int s4 = 0; s4 < 23; ++s4) {
    const int kb = kbase + s4 * 16 + kq;
    {
      const int k = kb;
      const bool ok = (k < NXQ);
      const double av = ok ? (double)gA[k] * ainv[k] : 0.0;
      const double bv = ok ? (double)gB[k] : 0.0;
      c0v = __builtin_amdgcn_mfma_f64_16x16x4f64(av, bv, c0v, 0, 0, 0);
    }
    {
      const int k = kb + 4;
      const bool ok = (k < NXQ);
      const double av = ok ? (double)gA[k] * ainv[k] : 0.0;
      const double bv = ok ? (double)gB[k] : 0.0;
      c1v = __builtin_amdgcn_mfma_f64_16x16x4f64(av, bv, c1v, 0, 0, 0);
    }
    {
      const int k = kb + 8;
      const bool ok = (k < NXQ);
      const double av = ok ? (double)gA[k] * ainv[k] : 0.0;
      const double bv = ok ? (double)gB[k] : 0.0;
      c2v = __builtin_amdgcn_mfma_f64_16x16x4f64(av, bv, c2v, 0, 0, 0);
    }
    {
      const int k = kb + 12;
      const bool ok = (k < NXQ);
      const double av = ok ? (double)gA[k] * ainv[k] : 0.0;
      const double bv = ok ? (double)gB[k] : 0.0;
      c3v = __builtin_amdgcn_mfma_f64_16x16x4f64(av, bv, c3v, 0, 0, 0);
    }
  }
#pragma unroll
  for (int e = 0; e < 4; ++e) {
    const double v = (c0v[e] + c1v[e]) + (c2v[e] + c3v[e]);
    psum[khalf * 1024 + unit * 256 + rowm[e] * 16 + colm[e]] = v;
  }
  __syncthreads();
  for (int idx = tid; idx < 1024; idx += 512) {
    const int r = idx >> 5, c = idx & 31;
    const int o = ((r >> 4) * 2 + (c >> 4)) * 256 + (r & 15) * 16 + (c & 15);
    Sgb[tile * 1024 + idx] = psum[o] + psum[1024 + o];
  }
}

// ---------------------------------------------------------------------------
// ps (pre-loop only): grid (16, 12) x 512 — b on x for per-batch XCD locality.
// ---------------------------------------------------------------------------
__global__ __launch_bounds__(512)
void ps_kernel(const float* __restrict__ G2, double* __restrict__ ws) {
  const int b = blockIdx.x, tile = blockIdx.y;
  const int tid = threadIdx.x, lane = tid & 63;
  extern __shared__ double sm[];
  double* st = ws + OFF_ST + b * STB;   // set 0
  {
    double* uvec = sm;
    double* part = sm + 128;
    double* yl   = sm + 640;
    const int c0 = tile * 64;
    if (tid < M2Q) uvec[tid] = ws[OFF_Q2 + b * M2Q + tid];
    __syncthreads();
    const int kk = tid & 63, rq = tid >> 6;
    const int k = c0 + kk;
    const int kg = (k < NXQ) ? k : (NXQ - 1);
    {
      const float* gp = G2 + (rq * 16) * NXQ + kg;
      double acc = 0.0;
#pragma unroll
      for (int j = 0; j < 16; ++j) acc = fma((double)gp[j * NXQ], uvec[rq * 16 + j], acc);
      part[rq * 64 + kk] = acc;
    }
    __syncthreads();
    if (tid < 64) {
      const int k2 = c0 + tid;
      double y = 0.0;
      if (k2 < NXQ) {
        double w = 0.0;
#pragma unroll
        for (int q = 0; q < 8; ++q) w += part[q * 64 + tid];
        const double rhsk = -(QPEN_ * st[ST_Z + k2] + ws[OFF_P + b * NXQ + k2]
                              - st[ST_LAM + k2] - st[ST_V + k2] + w);
        y = st[ST_AINV + k2] * rhsk;
        st[ST_Y + k2] = y;
      }
      yl[tid] = y;
    }
    __syncthreads();
    {
      // butterfly multi-row reduce: same pairwise tree as wred_sum -> bit-exact
      const double yv = yl[lane];
      double pp[16];
#pragma unroll
      for (int jr = 0; jr < 16; ++jr)
        pp[jr] = (double)G2[((tid >> 6) * 16 + jr) * NXQ + kg] * yv;
#pragma unroll
      for (int st2 = 0; st2 < 4; ++st2) {
        const int m = 32 >> st2, half = 8 >> st2;
        const bool hi = (lane & m) != 0;
#pragma unroll
        for (int r = 0; r < 8; ++r) {
          if (r < half) {
            const double send = hi ? pp[r] : pp[r + half];
            const double recv = __shfl_xor(send, m, 64);
            pp[r] = (hi ? pp[r + half] : pp[r]) + recv;
          }
        }
      }
      double tot = pp[0];
      tot += __shfl_xor(tot, 2, 64);
      tot += __shfl_xor(tot, 1, 64);
      if ((lane & 3) == 0)
        ws[OFF_TP + (tile * BQ + b) * M2Q + (tid >> 6) * 16 + ((lane >> 2) & 15)] = tot;
    }
    __syncthreads();
  }
  if (tile < 10) {
    int rowm[4], colm[4];
    mfma_cdmap(rowm, colm);
    sbuild_mfma(G2, st + ST_AINV, sm + P_PSUM, ws + OFF_SG + b * 10240, tile,
                rowm, colm);
  }
}

// ---------------------------------------------------------------------------
// dps: grid (16, 12) x 512 (b on x -> per-batch XCD locality). Redundant
// factor+solve per block, then fused dz+alpha + own-slice state update +
// prep chunk + MFMA sbuild tile.
// ---------------------------------------------------------------------------
__global__ __launch_bounds__(512, 1)
void dps_kernel(const float* __restrict__ G2, double* __restrict__ ws,
                float* __restrict__ out, const int ph, const int last) {
  const int b = blockIdx.x, chunk = blockIdx.y;
  const int tid = threadIdx.x, wave = tid >> 6, lane = tid & 63;
  extern __shared__ double sm[];
  double (*Sl)[129] = (double(*)[129])(sm + L_SL);
  double* us   = sm + L_US;     // u — survives into dps phases
  double* invd = sm + L_INVD;   // invd during factor; g2b after
  double* red2 = sm + L_RED2;   // 32 x 17
  const double* R = ws + OFF_ST + ph * BQ * STB + b * STB;
  double*       W = ws + OFF_ST + (1 - ph) * BQ * STB + b * STB;
  double* Sgb  = ws + OFF_SG + b * 10240;
  const int c0 = chunk * 64;

  // ===== SOLVE PHASE =====
#pragma unroll
  for (int t = 0; t < 10; ++t) {
    const int R0 = TRI_R[t] * 32, C0 = TRI_C[t] * 32;
    for (int e = tid; e < 1024; e += 512) {
      const int r = e >> 5, c = e & 31;
      Sl[R0 + r][C0 + c] = Sgb[t * 1024 + e];
    }
  }
  if (tid < M2Q) {
    double t = 0.0;
#pragma unroll
    for (int c = 0; c < 12; ++c) t += ws[OFF_TP + (c * BQ + b) * M2Q + tid];
    us[tid] = t;
  }
  __syncthreads();
  if (tid < M2Q) Sl[tid][tid] += R[ST_S + NXQ + tid] / R[ST_LAM + NXQ + tid];
  __syncthreads();

  int rowm[4], colm[4];
  mfma_cdmap(rowm, colm);
  const int rc16 = lane & 15, kq4 = lane >> 4;

  auto panel16 = [&](const int K0) {
    const int r = lane;
    double a[16];
#pragma unroll
    for (int c = 0; c < 16; ++c) a[c] = Sl[K0 + r][K0 + c];
#pragma unroll
    for (int c = 0; c < 16; ++c) {
      const double dcc = __shfl(a[c], c, 64);
      const double rs = rsqrt64(dcc);
      a[c] *= rs;
      if (lane == c) invd[K0 + c] = rs;
#pragma unroll
      for (int k2 = c + 1; k2 < 16; ++k2) {
        const double lkc = __shfl(a[c], k2, 64);
        a[k2] = fma(-a[c], lkc, a[k2]);
      }
    }
#pragma unroll
    for (int c = 0; c < 16; ++c) Sl[K0 + r][K0 + c] = a[c];
  };

  auto tile_upd = [&](const int K0, const int i0, const int j0) {
    d4 tacc;
#pragma unroll
    for (int e = 0; e < 4; ++e) tacc[e] = Sl[i0 + rowm[e]][j0 + colm[e]];
#pragma unroll
    for (int m = 0; m < 4; ++m) {
      const double av = -Sl[i0 + rc16][K0 + 4 * m + kq4];
      const double bv =  Sl[j0 + rc16][K0 + 4 * m + kq4];
      tacc = __builtin_amdgcn_mfma_f64_16x16x4f64(av, bv, tacc, 0, 0, 0);
    }
#pragma unroll
    for (int e = 0; e < 4; ++e) Sl[i0 + rowm[e]][j0 + colm[e]] = tacc[e];
  };

  if (wave == 0 && lane < 16) panel16(0);
  __syncthreads();

  for (int kb = 0; kb < 8; ++kb) {
    const int K0 = kb * 16, J0 = K0 + 16, T = 128 - J0;
    // row update (+ u forward-subst on the isU thread)
    if (tid <= T) {
      const bool isU = (tid == T);
      double l[16];
      if (isU) {
#pragma unroll
        for (int c = 0; c < 16; ++c) l[c] = us[K0 + c];
      } else {
#pragma unroll
        for (int c = 0; c < 16; ++c) l[c] = Sl[J0 + tid][K0 + c];
      }
#pragma unroll
      for (int c = 0; c < 16; ++c) {
        const double lc = l[c] * invd[K0 + c];
        l[c] = lc;
#pragma unroll
        for (int k2 = c + 1; k2 < 16; ++k2)
          l[k2] = fma(-lc, Sl[K0 + k2][K0 + c], l[k2]);
      }
      if (isU) {
#pragma unroll
        for (int c = 0; c < 16; ++c) us[K0 + c] = l[c];
      } else {
#pragma unroll
        for (int c = 0; c < 16; ++c) Sl[J0 + tid][K0 + c] = l[c];
      }
    }
    __syncthreads();

    if (kb < 7) {
      // us-elim (waves 0-1) + next diag tile update (wave 7) — disjoint
      if (tid < T) {
        double acc = 0.0;
#pragma unroll
        for (int c = 0; c < 16; ++c) acc = fma(Sl[J0 + tid][K0 + c], us[K0 + c], acc);
        us[J0 + tid] -= acc;
      }
      if (wave == 7) tile_upd(K0, J0, J0);
      __syncthreads();
      // lookahead: panel(kb+1) on wave0 || remaining trailing tiles on waves 1-7
      const int Tb = 7 - kb;
      const int nt = (Tb * (Tb + 1)) >> 1;
      if (wave == 0) {
        if (lane < 16) panel16(J0);
      } else {
        for (int idx = wave; idx < nt; idx += 7)
          tile_upd(K0, J0 + TRL_R[idx] * 16, J0 + TRL_C[idx] * 16);
      }
      __syncthreads();
    }
  }

  // back-substitution (reduce folded into the serial 16-lane section)
  for (int kb = 7; kb >= 0; --kb) {
    const int K0 = kb * 16;
    if (kb < 7) {
      const int c = tid & 15, ch = tid >> 4;
      double part = 0.0;
      for (int k = K0 + 16 + ch; k < 128; k += 32) part = fma(Sl[k][K0 + c], us[k], part);
      red2[ch * 17 + c] = part;
    }
    __syncthreads();
    if (wave == 0 && lane < 16) {
      const int j = lane;
      double x = us[K0 + j];
      if (kb < 7) {
        double acc = 0.0;
#pragma unroll
        for (int q = 0; q < 32; ++q) acc += red2[q * 17 + j];
        x -= acc;
      }
      double colv[16];
#pragma unroll
      for (int c = 0; c < 16; ++c) colv[c] = Sl[K0 + c][K0 + j];
      const double iv = invd[K0 + j];
#pragma unroll
      for (int cc = 0; cc < 16; ++cc) {
        const int c = 15 - cc;
        const double xiv = x * iv;
        const double uc = __shfl(xiv, c, 64);
        if (j == c) x = xiv;
        else if (j < c) x = fma(-colv[c], uc, x);
      }
      us[K0 + j] = x;
    }
    __syncthreads();
  }
  // g2b = D2inv * u (into invd's dead slot)
  if (tid < M2Q) invd[tid] = (R[ST_S + NXQ + tid] / R[ST_LAM + NXQ + tid]) * us[tid];
  __syncthreads();
  double* g2b = invd;

  // ===== DPS PHASES (aliased into dead Sl region) =====
  double* dzl   = sm + D_DZ;
  double* red   = sm + D_RED;
  double* sc    = sm + D_SC;
  double* ainvn = sm + D_AINV;
  double* q2l   = sm + D_Q2;
  double* yl    = sm + D_YL;
  double* snew  = sm + D_SN;
  double* lnew  = sm + D_LN;
  double* part  = sm + D_PART;
  double* psum  = sm + D_PSUM;

  // fused dz + alpha-prep: dz's k mapping matches alpha's i<NXQ mapping, so
  // each thread uses its own freshly computed dz (no barrier in between).
  // M2 tail handled by tid<128. min-reduce is order-free -> bit-exact.
  double lmin = 1e300;
  for (int k = tid; k < NXQ; k += 512) {
    double accv = 0.0;
    const float* gp = G2 + k;
#pragma unroll 16
    for (int r = 0; r < M2Q; ++r) accv = fma((double)gp[r * NXQ], us[r], accv);
    const double dzv = R[ST_Y + k] - R[ST_AINV + k] * accv;
    dzl[k] = dzv;
    const double si = R[ST_S + k], li = R[ST_LAM + k], di = li / si;
    const double dsi = dzv - R[ST_RP + k];
    const double dlami = R[ST_V + k] - di * dzv;
    snew[k] = dsi; lnew[k] = dlami;
    if (dsi < 0.0)   lmin = fmin(lmin, -si / dsi);
    if (dlami < 0.0) lmin = fmin(lmin, -li / dlami);
  }
  if (tid < M2Q) {
    const int i = NXQ + tid;
    const double si = R[ST_S + i], li = R[ST_LAM + i], di = li / si;
    const double g = g2b[tid];
    const double dsi = -R[ST_RP + i] - g;
    const double dlami = R[ST_V + i] + di * g;
    snew[i] = dsi; lnew[i] = dlami;
    if (dsi < 0.0)   lmin = fmin(lmin, -si / dsi);
    if (dlami < 0.0) lmin = fmin(lmin, -li / dlami);
  }
  lmin = wred_min(lmin);
  if (lane == 0) red[wave] = lmin;
  __syncthreads();
  if (tid == 0) {
    double m = red[0];
#pragma unroll
    for (int w = 1; w < 8; ++w) m = fmin(m, red[w]);
    sc[0] = fmin(1.0, 0.99 * m);
  }
  __syncthreads();
  const double alpha = sc[0];

  if (last) {
    const int k2 = c0 + (tid & 63);
    if (tid < 64 && k2 < NXQ)
      out[b * NXQ + k2] = (float)(R[ST_Z + k2] + alpha * dzl[k2]);
    return;
  }

  // s/lam update + musum (reads stashed dsi/dlami; fixed order across blocks)
  double musum = 0.0;
  for (int i = tid; i < MQ; i += 512) {
    const double si = R[ST_S + i], li = R[ST_LAM + i];
    const double sn = si + alpha * snew[i], ln = li + alpha * lnew[i];
    snew[i] = sn; lnew[i] = ln;
    musum += sn * ln;
  }
  musum = wred_sum(musum);
  if (lane == 0) red[wave] = musum;
  __syncthreads();
  if (tid == 0) {
    double t = 0.0;
#pragma unroll
    for (int w = 0; w < 8; ++w) t += red[w];
    sc[1] = SIGMA_ * (t / (double)MQ);
  }
  __syncthreads();
  const double smu = sc[1];

  // derived state; own-slice writes to W
  for (int i = tid; i < MQ; i += 512) {
    const double sn = snew[i], ln = lnew[i], di = ln / sn;
    if (i < NXQ) {
      const double zn = R[ST_Z + i] + alpha * dzl[i];
      const double rpn = sn - zn;
      const double vn = smu / sn - ln + di * rpn;
      const double an = 1.0 / (QPEN_ + di);
      ainvn[i] = an;
      if ((i >> 6) == chunk) {
        W[ST_Z + i] = zn; W[ST_S + i] = sn; W[ST_LAM + i] = ln;
        W[ST_RP + i] = rpn; W[ST_V + i] = vn; W[ST_AINV + i] = an;
      }
    } else {
      const int m = i - NXQ;
      const double gzn = R[ST_GZ + m] + alpha * g2b[m];
      const double rpn = gzn + sn - ws[OFF_H2 + m];
      const double vn = smu / sn - ln + di * rpn;
      q2l[m] = ln + vn;
      if (chunk == 0) {
        W[ST_S + i] = sn; W[ST_LAM + i] = ln;
        W[ST_RP + i] = rpn; W[ST_V + i] = vn; W[ST_GZ + m] = gzn;
      }
    }
  }
  __syncthreads();

  // prep chunk (rhs, y, t partials) from LDS-local new state
  {
    const int kk = tid & 63, rq = tid >> 6;
    const int k = c0 + kk;
    const int kg = (k < NXQ) ? k : (NXQ - 1);
    {
      const float* gp = G2 + (rq * 16) * NXQ + kg;
      double acc = 0.0;
#pragma unroll
      for (int j = 0; j < 16; ++j) acc = fma((double)gp[j * NXQ], q2l[rq * 16 + j], acc);
      part[rq * 64 + kk] = acc;
    }
    __syncthreads();
    if (tid < 64) {
      const int k2 = c0 + tid;
      double y = 0.0;
      if (k2 < NXQ) {
        double w = 0.0;
#pragma unroll
        for (int q = 0; q < 8; ++q) w += part[q * 64 + tid];
        const double sn = snew[k2], ln = lnew[k2], di = ln / sn;
        const double zn = R[ST_Z + k2] + alpha * dzl[k2];
        const double rpn = sn - zn;
        const double vn = smu / sn - ln + di * rpn;
        const double rhsk = -(QPEN_ * zn + ws[OFF_P + b * NXQ + k2] - ln - vn + w);
        y = ainvn[k2] * rhsk;
        W[ST_Y + k2] = y;
      }
      yl[tid] = y;
    }
    __syncthreads();
    {
      // butterfly multi-row reduce (same summation tree as wred_sum)
      const double yv = yl[lane];
      double pp[16];
#pragma unroll
      for (int jr = 0; jr < 16; ++jr)
        pp[jr] = (double)G2[((tid >> 6) * 16 + jr) * NXQ + kg] * yv;
#pragma unroll
      for (int st2 = 0; st2 < 4; ++st2) {
        const int m = 32 >> st2, half = 8 >> st2;
        const bool hi = (lane & m) != 0;
#pragma unroll
        for (int r = 0; r < 8; ++r) {
          if (r < half) {
            const double send = hi ? pp[r] : pp[r + half];
            const double recv = __shfl_xor(send, m, 64);
            pp[r] = (hi ? pp[r + half] : pp[r]) + recv;
          }
        }
      }
      double tot = pp[0];
      tot += __shfl_xor(tot, 2, 64);
      tot += __shfl_xor(tot, 1, 64);
      if ((lane & 3) == 0)
        ws[OFF_TP + (chunk * BQ + b) * M2Q + (tid >> 6) * 16 + ((lane >> 2) & 15)] = tot;
    }
    __syncthreads();
  }

  // sbuild tile (blocks 0..9) via MFMA with LDS ainvn
  if (chunk < 10)
    sbuild_mfma(G2, ainvn, psum, Sgb, chunk, rowm, colm);
}

extern "C" void kernel_launch(void* const* d_in, const int* in_sizes, int n_in,
                              void* d_out, int out_size, void* d_ws, size_t ws_size,
                              hipStream_t stream) {
  const float* puzzles = (const float*)d_in[0];
  const float* G2      = (const float*)d_in[1];
  const float* z2      = (const float*)d_in[2];
  const float* s2      = (const float*)d_in[3];
  float* out = (float*)d_out;
  double* ws = (double*)d_ws;

  (void)hipFuncSetAttribute(reinterpret_cast<const void*>(&dps_kernel),
                            hipFuncAttributeMaxDynamicSharedMemorySize, SH_FUSED);
  (void)hipFuncSetAttribute(reinterpret_cast<const void*>(&ps_kernel),
                            hipFuncAttributeMaxDynamicSharedMemorySize, SH_PS);

  init_kernel<<<dim3(16 + M2Q), dim3(512), 0, stream>>>(puzzles, G2, z2, s2, ws);
  ps_kernel<<<dim3(BQ, 12), dim3(512), SH_PS, stream>>>(G2, ws);
  for (int it = 0; it < 10; ++it) {
    const int ph = it & 1;
    dps_kernel<<<dim3(BQ, 12), dim3(512), SH_FUSED, stream>>>(G2, ws, out, ph, (it == 9) ? 1 : 0);
  }
}

// Round 6
// 829.515 us; speedup vs baseline: 1.2382x; 1.2382x over previous
//
#include <hip/hip_runtime.h>
#include <math.h>

#define NXQ 729
#define M2Q 128
#define MQ  857
#define BQ  16
#define QPEN_ 0.1
#define SIGMA_ 0.1

typedef double d4 __attribute__((ext_vector_type(4)));

// workspace offsets (in doubles)
constexpr int OFF_P    = 0;                        // 16x729
constexpr int OFF_H2   = OFF_P + BQ*NXQ;           // 128
constexpr int OFF_Q2   = OFF_H2 + M2Q;             // 16x128 (init -> pre-loop ps only)
constexpr int OFF_TP   = OFF_Q2 + BQ*M2Q;          // 12x16x128 t partials
// ping-pong state: 2 sets x 16 batches x STB
constexpr int ST_Z    = 0;      // 729
constexpr int ST_S    = 729;    // 857
constexpr int ST_LAM  = 1586;   // 857
constexpr int ST_RP   = 2443;   // 857
constexpr int ST_V    = 3300;   // 857
constexpr int ST_AINV = 4157;   // 729
constexpr int ST_Y    = 4886;   // 729
constexpr int ST_GZ   = 5615;   // 128
constexpr int STB     = 5743;
constexpr int OFF_ST  = OFF_TP + 12*BQ*M2Q;
// Sgb: 16 batches x 10 tiles x 2 K-halves x 1024 (tile-major, half inner)
constexpr int SGB_B   = 20480;
constexpr int OFF_SG  = OFF_ST + 2*BQ*STB;

// fused-kernel LDS layout (doubles): solve region 0..16512 reused by dps phases.
constexpr int L_SL   = 0;                  // 128 x 129 = 16512 (solve only)
constexpr int L_US   = 16512;              // 128  (u — persists into dps phases)
constexpr int L_INVD = 16640;              // 128  (invd; reused as g2b after back-subst)
constexpr int L_RED2 = 16768;              // 32 x 17 = 544
constexpr int SH_FUSED = (16768 + 544) * 8;   // 138496 B -> 1 block/CU
// dps-phase aliases inside the dead Sl region:
constexpr int D_DZ   = 0;      // 729 (pad 736)
constexpr int D_RED  = 736;    // 8
constexpr int D_SC   = 744;    // 8
constexpr int D_Q2   = 752;    // 128
constexpr int D_YL   = 880;    // 64
constexpr int D_SN   = 944;    // 857
constexpr int D_LN   = 1801;   // 857
constexpr int D_PART = 2658;   // 512 (ends 3170)
constexpr int D_AINV = 12672;  // 729 (ends 13401) — above the sbuild arena
// sbuild arena: 4 waves x (As 48x33=1584 + Bs 1584) = 12672 doubles at sm+0
constexpr int AR_W   = 3168;
constexpr int SH_PS  = 12672 * 8;          // 101376 B

__device__ __constant__ int TRI_R[10] = {0,1,1,2,2,2,3,3,3,3};
__device__ __constant__ int TRI_C[10] = {0,0,1,0,1,2,0,1,2,3};
// lower-triangle tile enumeration up to 7x7 (trailing update, r>=c)
__device__ __constant__ int TRL_R[28] = {0,1,1,2,2,2,3,3,3,3,4,4,4,4,4,5,5,5,5,5,5,6,6,6,6,6,6,6};
__device__ __constant__ int TRL_C[28] = {0,0,1,0,1,2,0,1,2,3,0,1,2,3,4,0,1,2,3,4,5,0,1,2,3,4,5,6};

__device__ __forceinline__ double wred_sum(double v) {
#pragma unroll
  for (int off = 32; off > 0; off >>= 1) v += __shfl_down(v, off, 64);
  return v;
}
__device__ __forceinline__ double wred_min(double v) {
#pragma unroll
  for (int off = 32; off > 0; off >>= 1) v = fmin(v, __shfl_down(v, off, 64));
  return v;
}
__device__ __forceinline__ double rsqrt64(double x) {
  double r = (double)rsqrtf((float)x);
  r = r * (1.5 - 0.5 * x * r * r);
  r = r * (1.5 - 0.5 * x * r * r);
  return r;
}

// C/D lane->(row,col) map for mfma_f64_16x16x4, derived via identity-MFMA.
__device__ __forceinline__ void mfma_cdmap(int* rowm, int* colm) {
  const int lane = threadIdx.x & 63;
  const int rc = lane & 15, kq = lane >> 4;
  const double avr = (kq == 0) ? (double)rc : 0.0;
  const double bv1 = (kq == 0) ? 1.0 : 0.0;
  const double av1 = (kq == 0) ? 1.0 : 0.0;
  const double bvc = (kq == 0) ? (double)rc : 0.0;
  d4 zero = {0.0, 0.0, 0.0, 0.0};
  d4 dr = __builtin_amdgcn_mfma_f64_16x16x4f64(avr, bv1, zero, 0, 0, 0);
  d4 dc = __builtin_amdgcn_mfma_f64_16x16x4f64(av1, bvc, zero, 0, 0, 0);
#pragma unroll
  for (int e = 0; e < 4; ++e) { rowm[e] = (int)dr[e]; colm[e] = (int)dc[e]; }
}

// ---------------------------------------------------------------------------
// init: grid 144 x 512 (verbatim)
// ---------------------------------------------------------------------------
__global__ __launch_bounds__(512)
void init_kernel(const float* __restrict__ puzzles, const float* __restrict__ G2,
                 const float* __restrict__ z2in, const float* __restrict__ s2in,
                 double* __restrict__ ws) {
  const int blk = blockIdx.x;
  const int tid = threadIdx.x, wave = tid >> 6, lane = tid & 63;
  __shared__ double sm[32];
  if (blk < BQ) {
    const int bb = blk;
    double* st = ws + OFF_ST + bb * STB;   // set 0
    for (int i = tid; i < NXQ; i += 512) {
      ws[OFF_P + bb * NXQ + i] = -(double)puzzles[bb * NXQ + i];
      st[ST_Z + i] = 0.0;
      st[ST_AINV + i] = 1.0 / (QPEN_ + 1.0);
      st[ST_RP + i] = 1.0;
      st[ST_V + i] = SIGMA_;
    }
    for (int i = tid; i < MQ; i += 512) { st[ST_S + i] = 1.0; st[ST_LAM + i] = 1.0; }
    if (tid < M2Q) st[ST_GZ + tid] = 0.0;
  } else {
    const int r = blk - 16;
    double acc = 0.0;
    for (int kx = tid; kx < NXQ; kx += 512)
      acc += (double)G2[r * NXQ + kx] * (double)z2in[kx];
    acc = wred_sum(acc);
    if (lane == 0) sm[wave] = acc;
    __syncthreads();
    if (tid == 0) {
      double t = 0.0;
#pragma unroll
      for (int w = 0; w < 8; ++w) t += sm[w];
      const double h2r = t + (double)s2in[r];
      ws[OFF_H2 + r] = h2r;
      sm[16] = h2r;
    }
    __syncthreads();
    if (tid < BQ) {
      double* st = ws + OFF_ST + tid * STB;
      const double rp2 = 1.0 - sm[16];
      st[ST_RP + NXQ + r] = rp2;
      st[ST_V  + NXQ + r] = rp2 - 0.9;
      ws[OFF_Q2 + tid * M2Q + r] = rp2 + 0.1;
    }
  }
}

// ---------------------------------------------------------------------------
// sbuild half-K unit via MFMA fed from LDS: S_half(32x32) = sum over the
// half's k-range of (G2[R0..]*ainv)(k) * G2[C0..](k). Waves 0-3 each own 92
// k's (2 chunks of 48, zero-padded), staged k-major As[k*33+r] with R4's
// register-prefetch pipeline (coalesced global reads). Compute: per step 4
// ds_read_b64 + 4 MFMA (2x2 sub-tiles, accumulators persist across chunks).
// Cross-wave combine via the 4 arenas as in R4.
// ---------------------------------------------------------------------------
__device__ __forceinline__ void sbuild_half(const float* __restrict__ G2,
                                            const double* __restrict__ ainv,
                                            double* __restrict__ arena,
                                            double* __restrict__ Sgb,
                                            const int tile, const int half,
                                            const int* rowm, const int* colm) {
  const int tid = threadIdx.x, wave = tid >> 6, lane = tid & 63;
  const int R0 = TRI_R[tile] * 32, C0 = TRI_C[tile] * 32;
  double* As = arena + wave * AR_W;   // waves 0-3 only
  double* Bs = As + 1584;
  const int kw0 = half * 368 + wave * 92;
  const int kwend = min(kw0 + 92, NXQ);
  const int kk16 = lane & 15, rsub = lane >> 4;
  const int rc = lane & 15, kq = lane >> 4;
  d4 c00 = {0.0, 0.0, 0.0, 0.0}, c01 = c00, c10 = c00, c11 = c00;
  float pa[24], pb[24];
  if (wave < 4) {
    // prefetch chunk 0 (clamped address; validity applied at LDS-write time)
#pragma unroll
    for (int it = 0; it < 24; ++it) {
      const int kk = (it >> 3) * 16 + kk16;   // 0..47
      const int rr = (it & 7) * 4 + rsub;     // 0..31
      const int k = kw0 + kk;
      const int kc = (k < kwend) ? k : (kwend - 1);
      pa[it] = G2[(R0 + rr) * NXQ + kc];
      pb[it] = G2[(C0 + rr) * NXQ + kc];
    }
  }
  for (int ch = 0; ch < 2; ++ch) {
    __syncthreads();
    if (wave < 4) {
#pragma unroll
      for (int it = 0; it < 24; ++it) {
        const int kk = (it >> 3) * 16 + kk16;
        const int rr = (it & 7) * 4 + rsub;
        const int k = kw0 + ch * 48 + kk;
        const bool ok = (k < kwend);
        const double aik = ok ? ainv[k] : 0.0;
        As[kk * 33 + rr] = ok ? (double)pa[it] * aik : 0.0;
        Bs[kk * 33 + rr] = ok ? (double)pb[it] : 0.0;
      }
      if (ch == 0) {
#pragma unroll
        for (int it = 0; it < 24; ++it) {
          const int kk = (it >> 3) * 16 + kk16;
          const int rr = (it & 7) * 4 + rsub;
          const int k = kw0 + 48 + kk;
          const int kc = (k < kwend) ? k : (kwend - 1);
          pa[it] = G2[(R0 + rr) * NXQ + kc];
          pb[it] = G2[(C0 + rr) * NXQ + kc];
        }
      }
    }
    __syncthreads();
    if (wave < 4) {
#pragma unroll
      for (int s = 0; s < 12; ++s) {
        const int ko = (s * 4 + kq) * 33;
        const double a0 = As[ko + rc],      a1 = As[ko + 16 + rc];
        const double b0 = Bs[ko + rc],      b1 = Bs[ko + 16 + rc];
        c00 = __builtin_amdgcn_mfma_f64_16x16x4f64(a0, b0, c00, 0, 0, 0);
        c01 = __builtin_amdgcn_mfma_f64_16x16x4f64(a0, b1, c01, 0, 0, 0);
        c10 = __builtin_amdgcn_mfma_f64_16x16x4f64(a1, b0, c10, 0, 0, 0);
        c11 = __builtin_amdgcn_mfma_f64_16x16x4f64(a1, b1, c11, 0, 0, 0);
      }
    }
  }
  __syncthreads();
  if (wave < 4) {
#pragma unroll
    for (int e = 0; e < 4; ++e) {
      As[rowm[e] * 33 + colm[e]]              = c00[e];
      As[rowm[e] * 33 + 16 + colm[e]]         = c01[e];
      As[(16 + rowm[e]) * 33 + colm[e]]       = c10[e];
      As[(16 + rowm[e]) * 33 + 16 + colm[e]]  = c11[e];
    }
  }
  __syncthreads();
  for (int idx = tid; idx < 1024; idx += 512) {
    const int r = idx >> 5, c = idx & 31;
    const int o = r * 33 + c;
    const double v = arena[o] + arena[AR_W + o] + arena[2*AR_W + o] + arena[3*AR_W + o];
    Sgb[(tile * 2 + half) * 1024 + idx] = v;
  }
}

// unit u in [0,20): tile = u>>1, half = u&1. Blocks y<12: unit y (prep+1 unit);
// blocks y>=12: units 12+(y-12)*2 and +1 (2 units, no prep).
__device__ __forceinline__ void run_sbuild_units(const float* __restrict__ G2,
                                                 const double* __restrict__ ainv,
                                                 double* __restrict__ arena,
                                                 double* __restrict__ Sgb,
                                                 const int y,
                                                 const int* rowm, const int* colm) {
  if (y < 12) {
    sbuild_half(G2, ainv, arena, Sgb, y >> 1, y & 1, rowm, colm);
  } else {
    const int u0 = 12 + (y - 12) * 2;
    sbuild_half(G2, ainv, arena, Sgb, u0 >> 1, u0 & 1, rowm, colm);
    sbuild_half(G2, ainv, arena, Sgb, (u0 + 1) >> 1, (u0 + 1) & 1, rowm, colm);
  }
}

// ---------------------------------------------------------------------------
// ps (pre-loop only): grid (16, 16) x 512 — b on x for per-batch XCD locality.
// y<12: prep tile y + sbuild unit y; y>=12: 2 sbuild units.
// ---------------------------------------------------------------------------
__global__ __launch_bounds__(512)
void ps_kernel(const float* __restrict__ G2, double* __restrict__ ws) {
  const int b = blockIdx.x, tile = blockIdx.y;
  const int tid = threadIdx.x, lane = tid & 63;
  extern __shared__ double sm[];
  double* st = ws + OFF_ST + b * STB;   // set 0
  if (tile < 12) {
    double* uvec = sm;
    double* part = sm + 128;
    double* yl   = sm + 640;
    const int c0 = tile * 64;
    if (tid < M2Q) uvec[tid] = ws[OFF_Q2 + b * M2Q + tid];
    __syncthreads();
    const int kk = tid & 63, rq = tid >> 6;
    const int k = c0 + kk;
    const int kg = (k < NXQ) ? k : (NXQ - 1);
    {
      const float* gp = G2 + (rq * 16) * NXQ + kg;
      double acc = 0.0;
#pragma unroll
      for (int j = 0; j < 16; ++j) acc = fma((double)gp[j * NXQ], uvec[rq * 16 + j], acc);
      part[rq * 64 + kk] = acc;
    }
    __syncthreads();
    if (tid < 64) {
      const int k2 = c0 + tid;
      double y = 0.0;
      if (k2 < NXQ) {
        double w = 0.0;
#pragma unroll
        for (int q = 0; q < 8; ++q) w += part[q * 64 + tid];
        const double rhsk = -(QPEN_ * st[ST_Z + k2] + ws[OFF_P + b * NXQ + k2]
                              - st[ST_LAM + k2] - st[ST_V + k2] + w);
        y = st[ST_AINV + k2] * rhsk;
        st[ST_Y + k2] = y;
      }
      yl[tid] = y;
    }
    __syncthreads();
    {
      // butterfly multi-row reduce: same pairwise tree as wred_sum -> bit-exact
      const double yv = yl[lane];
      double pp[16];
#pragma unroll
      for (int jr = 0; jr < 16; ++jr)
        pp[jr] = (double)G2[((tid >> 6) * 16 + jr) * NXQ + kg] * yv;
#pragma unroll
      for (int st2 = 0; st2 < 4; ++st2) {
        const int m = 32 >> st2, half = 8 >> st2;
        const bool hi = (lane & m) != 0;
#pragma unroll
        for (int r = 0; r < 8; ++r) {
          if (r < half) {
            const double send = hi ? pp[r] : pp[r + half];
            const double recv = __shfl_xor(send, m, 64);
            pp[r] = (hi ? pp[r + half] : pp[r]) + recv;
          }
        }
      }
      double tot = pp[0];
      tot += __shfl_xor(tot, 2, 64);
      tot += __shfl_xor(tot, 1, 64);
      if ((lane & 3) == 0)
        ws[OFF_TP + (tile * BQ + b) * M2Q + (tid >> 6) * 16 + ((lane >> 2) & 15)] = tot;
    }
    __syncthreads();
  }
  {
    int rowm[4], colm[4];
    mfma_cdmap(rowm, colm);
    run_sbuild_units(G2, st + ST_AINV, sm, ws + OFF_SG + b * SGB_B, tile,
                     rowm, colm);
  }
}

// ---------------------------------------------------------------------------
// dps: grid (16, 16) x 512 (b on x -> per-batch XCD locality). Redundant
// factor+solve per block, then fused dz+alpha + own-slice state update +
// prep chunk (chunk<12) + sbuild units (half-K, MFMA-from-LDS).
// ---------------------------------------------------------------------------
__global__ __launch_bounds__(512, 1)
void dps_kernel(const float* __restrict__ G2, double* __restrict__ ws,
                float* __restrict__ out, const int ph, const int last) {
  const int b = blockIdx.x, chunk = blockIdx.y;
  const int tid = threadIdx.x, wave = tid >> 6, lane = tid & 63;
  extern __shared__ double sm[];
  double (*Sl)[129] = (double(*)[129])(sm + L_SL);
  double* us   = sm + L_US;     // u — survives into dps phases
  double* invd = sm + L_INVD;   // invd during factor; g2b after
  double* red2 = sm + L_RED2;   // 32 x 17
  const double* R = ws + OFF_ST + ph * BQ * STB + b * STB;
  double*       W = ws + OFF_ST + (1 - ph) * BQ * STB + b * STB;
  double* Sgb  = ws + OFF_SG + b * SGB_B;
  const int c0 = chunk * 64;

  // ===== SOLVE PHASE =====
#pragma unroll
  for (int t = 0; t < 10; ++t) {
    const int R0 = TRI_R[t] * 32, C0 = TRI_C[t] * 32;
    for (int e = tid; e < 1024; e += 512) {
      const int r = e >> 5, c = e & 31;
      Sl[R0 + r][C0 + c] = Sgb[(t * 2) * 1024 + e] + Sgb[(t * 2 + 1) * 1024 + e];
    }
  }
  if (tid < M2Q) {
    double t = 0.0;
#pragma unroll
    for (int c = 0; c < 12; ++c) t += ws[OFF_TP + (c * BQ + b) * M2Q + tid];
    us[tid] = t;
  }
  __syncthreads();
  if (tid < M2Q) Sl[tid][tid] += R[ST_S + NXQ + tid] / R[ST_LAM + NXQ + tid];
  __syncthreads();

  int rowm[4], colm[4];
  mfma_cdmap(rowm, colm);
  const int rc16 = lane & 15, kq4 = lane >> 4;

  auto panel16 = [&](const int K0) {
    const int r = lane;
    double a[16];
#pragma unroll
    for (int c = 0; c < 16; ++c) a[c] = Sl[K0 + r][K0 + c];
#pragma unroll
    for (int c = 0; c < 16; ++c) {
      const double dcc = __shfl(a[c], c, 64);
      const double rs = rsqrt64(dcc);
      a[c] *= rs;
      if (lane == c) invd[K0 + c] = rs;
#pragma unroll
      for (int k2 = c + 1; k2 < 16; ++k2) {
        const double lkc = __shfl(a[c], k2, 64);
        a[k2] = fma(-a[c], lkc, a[k2]);
      }
    }
#pragma unroll
    for (int c = 0; c < 16; ++c) Sl[K0 + r][K0 + c] = a[c];
  };

  auto tile_upd = [&](const int K0, const int i0, const int j0) {
    d4 tacc;
#pragma unroll
    for (int e = 0; e < 4; ++e) tacc[e] = Sl[i0 + rowm[e]][j0 + colm[e]];
#pragma unroll
    for (int m = 0; m < 4; ++m) {
      const double av = -Sl[i0 + rc16][K0 + 4 * m + kq4];
      const double bv =  Sl[j0 + rc16][K0 + 4 * m + kq4];
      tacc = __builtin_amdgcn_mfma_f64_16x16x4f64(av, bv, tacc, 0, 0, 0);
    }
#pragma unroll
    for (int e = 0; e < 4; ++e) Sl[i0 + rowm[e]][j0 + colm[e]] = tacc[e];
  };

  if (wave == 0 && lane < 16) panel16(0);
  __syncthreads();

  for (int kb = 0; kb < 8; ++kb) {
    const int K0 = kb * 16, J0 = K0 + 16, T = 128 - J0;
    // row update (+ u forward-subst on the isU thread)
    if (tid <= T) {
      const bool isU = (tid == T);
      double l[16];
      if (isU) {
#pragma unroll
        for (int c = 0; c < 16; ++c) l[c] = us[K0 + c];
      } else {
#pragma unroll
        for (int c = 0; c < 16; ++c) l[c] = Sl[J0 + tid][K0 + c];
      }
#pragma unroll
      for (int c = 0; c < 16; ++c) {
        const double lc = l[c] * invd[K0 + c];
        l[c] = lc;
#pragma unroll
        for (int k2 = c + 1; k2 < 16; ++k2)
          l[k2] = fma(-lc, Sl[K0 + k2][K0 + c], l[k2]);
      }
      if (isU) {
#pragma unroll
        for (int c = 0; c < 16; ++c) us[K0 + c] = l[c];
      } else {
#pragma unroll
        for (int c = 0; c < 16; ++c) Sl[J0 + tid][K0 + c] = l[c];
      }
    }
    __syncthreads();

    if (kb < 7) {
      // us-elim (waves 0-1) + next diag tile update (wave 7) — disjoint
      if (tid < T) {
        double acc = 0.0;
#pragma unroll
        for (int c = 0; c < 16; ++c) acc = fma(Sl[J0 + tid][K0 + c], us[K0 + c], acc);
        us[J0 + tid] -= acc;
      }
      if (wave == 7) tile_upd(K0, J0, J0);
      __syncthreads();
      // lookahead: panel(kb+1) on wave0 || remaining trailing tiles on waves 1-7
      const int Tb = 7 - kb;
      const int nt = (Tb * (Tb + 1)) >> 1;
      if (wave == 0) {
        if (lane < 16) panel16(J0);
      } else {
        for (int idx = wave; idx < nt; idx += 7)
          tile_upd(K0, J0 + TRL_R[idx] * 16, J0 + TRL_C[idx] * 16);
      }
      __syncthreads();
    }
  }

  // back-substitution (reduce folded into the serial 16-lane section)
  for (int kb = 7; kb >= 0; --kb) {
    const int K0 = kb * 16;
    if (kb < 7) {
      const int c = tid & 15, ch = tid >> 4;
      double part = 0.0;
      for (int k = K0 + 16 + ch; k < 128; k += 32) part = fma(Sl[k][K0 + c], us[k], part);
      red2[ch * 17 + c] = part;
    }
    __syncthreads();
    if (wave == 0 && lane < 16) {
      const int j = lane;
      double x = us[K0 + j];
      if (kb < 7) {
        double acc = 0.0;
#pragma unroll
        for (int q = 0; q < 32; ++q) acc += red2[q * 17 + j];
        x -= acc;
      }
      double colv[16];
#pragma unroll
      for (int c = 0; c < 16; ++c) colv[c] = Sl[K0 + c][K0 + j];
      const double iv = invd[K0 + j];
#pragma unroll
      for (int cc = 0; cc < 16; ++cc) {
        const int c = 15 - cc;
        const double xiv = x * iv;
        const double uc = __shfl(xiv, c, 64);
        if (j == c) x = xiv;
        else if (j < c) x = fma(-colv[c], uc, x);
      }
      us[K0 + j] = x;
    }
    __syncthreads();
  }
  // g2b = D2inv * u (into invd's dead slot)
  if (tid < M2Q) invd[tid] = (R[ST_S + NXQ + tid] / R[ST_LAM + NXQ + tid]) * us[tid];
  __syncthreads();
  double* g2b = invd;

  // ===== DPS PHASES (aliased into dead Sl region) =====
  double* dzl   = sm + D_DZ;
  double* red   = sm + D_RED;
  double* sc    = sm + D_SC;
  double* ainvn = sm + D_AINV;
  double* q2l   = sm + D_Q2;
  double* yl    = sm + D_YL;
  double* snew  = sm + D_SN;
  double* lnew  = sm + D_LN;
  double* part  = sm + D_PART;

  // fused dz + alpha-prep (per-element; min-reduce order-free -> bit-exact)
  double lmin = 1e300;
  for (int k = tid; k < NXQ; k += 512) {
    double accv = 0.0;
    const float* gp = G2 + k;
#pragma unroll 16
    for (int r = 0; r < M2Q; ++r) accv = fma((double)gp[r * NXQ], us[r], accv);
    const double dzv = R[ST_Y + k] - R[ST_AINV + k] * accv;
    dzl[k] = dzv;
    const double si = R[ST_S + k], li = R[ST_LAM + k], di = li / si;
    const double dsi = dzv - R[ST_RP + k];
    const double dlami = R[ST_V + k] - di * dzv;
    snew[k] = dsi; lnew[k] = dlami;
    if (dsi < 0.0)   lmin = fmin(lmin, -si / dsi);
    if (dlami < 0.0) lmin = fmin(lmin, -li / dlami);
  }
  if (tid < M2Q) {
    const int i = NXQ + tid;
    const double si = R[ST_S + i], li = R[ST_LAM + i], di = li / si;
    const double g = g2b[tid];
    const double dsi = -R[ST_RP + i] - g;
    const double dlami = R[ST_V + i] + di * g;
    snew[i] = dsi; lnew[i] = dlami;
    if (dsi < 0.0)   lmin = fmin(lmin, -si / dsi);
    if (dlami < 0.0) lmin = fmin(lmin, -li / dlami);
  }
  lmin = wred_min(lmin);
  if (lane == 0) red[wave] = lmin;
  __syncthreads();
  if (tid == 0) {
    double m = red[0];
#pragma unroll
    for (int w = 1; w < 8; ++w) m = fmin(m, red[w]);
    sc[0] = fmin(1.0, 0.99 * m);
  }
  __syncthreads();
  const double alpha = sc[0];

  if (last) {
    const int k2 = c0 + (tid & 63);
    if (tid < 64 && k2 < NXQ)
      out[b * NXQ + k2] = (float)(R[ST_Z + k2] + alpha * dzl[k2]);
    return;
  }

  // s/lam update + musum (reads stashed dsi/dlami; fixed order across blocks)
  double musum = 0.0;
  for (int i = tid; i < MQ; i += 512) {
    const double si = R[ST_S + i], li = R[ST_LAM + i];
    const double sn = si + alpha * snew[i], ln = li + alpha * lnew[i];
    snew[i] = sn; lnew[i] = ln;
    musum += sn * ln;
  }
  musum = wred_sum(musum);
  if (lane == 0) red[wave] = musum;
  __syncthreads();
  if (tid == 0) {
    double t = 0.0;
#pragma unroll
    for (int w = 0; w < 8; ++w) t += red[w];
    sc[1] = SIGMA_ * (t / (double)MQ);
  }
  __syncthreads();
  const double smu = sc[1];

  // derived state; own-slice writes to W (chunk>=12 matches no i -> safe)
  for (int i = tid; i < MQ; i += 512) {
    const double sn = snew[i], ln = lnew[i], di = ln / sn;
    if (i < NXQ) {
      const double zn = R[ST_Z + i] + alpha * dzl[i];
      const double rpn = sn - zn;
      const double vn = smu / sn - ln + di * rpn;
      const double an = 1.0 / (QPEN_ + di);
      ainvn[i] = an;
      if ((i >> 6) == chunk) {
        W[ST_Z + i] = zn; W[ST_S + i] = sn; W[ST_LAM + i] = ln;
        W[ST_RP + i] = rpn; W[ST_V + i] = vn; W[ST_AINV + i] = an;
      }
    } else {
      const int m = i - NXQ;
      const double gzn = R[ST_GZ + m] + alpha * g2b[m];
      const double rpn = gzn + sn - ws[OFF_H2 + m];
      const double vn = smu / sn - ln + di * rpn;
      q2l[m] = ln + vn;
      if (chunk == 0) {
        W[ST_S + i] = sn; W[ST_LAM + i] = ln;
        W[ST_RP + i] = rpn; W[ST_V + i] = vn; W[ST_GZ + m] = gzn;
      }
    }
  }
  __syncthreads();

  // prep chunk (rhs, y, t partials) — blocks with chunk<12 only
  if (chunk < 12) {
    const int kk = tid & 63, rq = tid >> 6;
    const int k = c0 + kk;
    const int kg = (k < NXQ) ? k : (NXQ - 1);
    {
      const float* gp = G2 + (rq * 16) * NXQ + kg;
      double acc = 0.0;
#pragma unroll
      for (int j = 0; j < 16; ++j) acc = fma((double)gp[j * NXQ], q2l[rq * 16 + j], acc);
      part[rq * 64 + kk] = acc;
    }
    __syncthreads();
    if (tid < 64) {
      const int k2 = c0 + tid;
      double y = 0.0;
      if (k2 < NXQ) {
        double w = 0.0;
#pragma unroll
        for (int q = 0; q < 8; ++q) w += part[q * 64 + tid];
        const double sn = snew[k2], ln = lnew[k2], di = ln / sn;
        const double zn = R[ST_Z + k2] + alpha * dzl[k2];
        const double rpn = sn - zn;
        const double vn = smu / sn - ln + di * rpn;
        const double rhsk = -(QPEN_ * zn + ws[OFF_P + b * NXQ + k2] - ln - vn + w);
        y = ainvn[k2] * rhsk;
        W[ST_Y + k2] = y;
      }
      yl[tid] = y;
    }
    __syncthreads();
    {
      // butterfly multi-row reduce (same summation tree as wred_sum)
      const double yv = yl[lane];
      double pp[16];
#pragma unroll
      for (int jr = 0; jr < 16; ++jr)
        pp[jr] = (double)G2[((tid >> 6) * 16 + jr) * NXQ + kg] * yv;
#pragma unroll
      for (int st2 = 0; st2 < 4; ++st2) {
        const int m = 32 >> st2, half = 8 >> st2;
        const bool hi = (lane & m) != 0;
#pragma unroll
        for (int r = 0; r < 8; ++r) {
          if (r < half) {
            const double send = hi ? pp[r] : pp[r + half];
            const double recv = __shfl_xor(send, m, 64);
            pp[r] = (hi ? pp[r + half] : pp[r]) + recv;
          }
        }
      }
      double tot = pp[0];
      tot += __shfl_xor(tot, 2, 64);
      tot += __shfl_xor(tot, 1, 64);
      if ((lane & 3) == 0)
        ws[OFF_TP + (chunk * BQ + b) * M2Q + (tid >> 6) * 16 + ((lane >> 2) & 15)] = tot;
    }
    __syncthreads();
  }

  // sbuild units (half-K, MFMA) with LDS ainvn
  run_sbuild_units(G2, ainvn, sm, Sgb, chunk, rowm, colm);
}

extern "C" void kernel_launch(void* const* d_in, const int* in_sizes, int n_in,
                              void* d_out, int out_size, void* d_ws, size_t ws_size,
                              hipStream_t stream) {
  const float* puzzles = (const float*)d_in[0];
  const float* G2      = (const float*)d_in[1];
  const float* z2      = (const float*)d_in[2];
  const float* s2      = (const float*)d_in[3];
  float* out = (float*)d_out;
  double* ws = (double*)d_ws;

  (void)hipFuncSetAttribute(reinterpret_cast<const void*>(&dps_kernel),
                            hipFuncAttributeMaxDynamicSharedMemorySize, SH_FUSED);
  (void)hipFuncSetAttribute(reinterpret_cast<const void*>(&ps_kernel),
                            hipFuncAttributeMaxDynamicSharedMemorySize, SH_PS);

  init_kernel<<<dim3(16 + M2Q), dim3(512), 0, stream>>>(puzzles, G2, z2, s2, ws);
  ps_kernel<<<dim3(BQ, 16), dim3(512), SH_PS, stream>>>(G2, ws);
  for (int it = 0; it < 10; ++it) {
    const int ph = it & 1;
    dps_kernel<<<dim3(BQ, 16), dim3(512), SH_FUSED, stream>>>(G2, ws, out, ph, (it == 9) ? 1 : 0);
  }
}